// Round 1
// 259.225 us; speedup vs baseline: 1.4796x; 1.4796x over previous
//
#include <hip/hip_runtime.h>
#include <stdint.h>

// ---- problem constants ----
#define PNUM  8
#define DDIM  512
#define ZDIM  64
#define ADIM  8
#define HDIM  512
#define BATCH 8192
#define KIN   72     // Z + A
#define NKS1  3      // layer1 k-steps of 32 (K padded 72->96)
#define NKS2  16     // layer2 k-steps (K=512)
#define NKS3  16     // layer3 k-steps (K=512)
#define NT12  32     // 512/16 neuron tiles (layers 1,2)
#define NT3   4      // 64/16 z tiles (layer 3)
#define TM    32     // batch rows per block (32: LDS 73KB -> 2 blocks/CU)
#define PXP   104    // Xb pitch (bf16 elems): 96 data + 8 pad
#define PHP   520    // H pitch: 512 + 8 pad

typedef __attribute__((ext_vector_type(8))) __bf16 bf16x8;
typedef __attribute__((ext_vector_type(4))) float  f32x4;

// ---- workspace layout ----
#define WS_COUNTS_I 0      // 8 counts
#define WS_OFFS_I   16     // 8 offsets
#define WS_CURS_I   32     // (unused, kept for layout stability)
#define WS_FLG_I    42     // 9 flags: 0=lat,1=act,2=W1,3=b1,4=W2,5=b2,6=W3,7=b3 (1=fp32,0=bf16); 8=idx64
#define WS_PERM_I   64     // 8192 row ids
#define WS_W1P_B    40960
#define WS_W2P_B    (WS_W1P_B + 64*NKS1*NT12*1024)            // +6291456
#define WS_W3P_B    (WS_W2P_B + 64*NKS2*NT12*1024)            // +33554432
#define WS_NEED_B   (WS_W3P_B + 64*NKS3*NT3*1024)             // -> 44081152

__device__ __forceinline__ float bf2f(ushort h){
  union { unsigned int u; float f; } v; v.u = ((unsigned int)h) << 16; return v.f;
}
__device__ __forceinline__ ushort f2bf(float f){
  union { float f; unsigned int u; } v; v.f = f;
  unsigned int u = v.u;
  return (ushort)((u + 0x7FFFu + ((u >> 16) & 1u)) >> 16);  // RNE
}
__device__ __forceinline__ unsigned int pk2(ushort lo, ushort hi){
  return (unsigned int)lo | ((unsigned int)hi << 16);
}
__device__ __forceinline__ float ldf(const void* p, size_t i, int f32){
  return f32 ? ((const float*)p)[i] : bf2f(((const ushort*)p)[i]);
}
__device__ __forceinline__ int ldidx(const void* p, int t, int i64){
  return i64 ? (int)((const long long*)p)[t] : ((const int*)p)[t];
}
__device__ __forceinline__ float4 ldbias4(const void* b, size_t off, int f32){
  if (f32) return *(const float4*)((const float*)b + off);
  ushort4 q = *(const ushort4*)((const ushort*)b + off);
  float4 r; r.x = bf2f(q.x); r.y = bf2f(q.y); r.z = bf2f(q.z); r.w = bf2f(q.w);
  return r;
}

// ---------- per-tensor runtime dtype detection ----------
__global__ void k_detect(const unsigned int* __restrict__ lat,
                         const unsigned int* __restrict__ act,
                         const unsigned int* __restrict__ w1,
                         const unsigned int* __restrict__ bb1,
                         const unsigned int* __restrict__ w2,
                         const unsigned int* __restrict__ bb2,
                         const unsigned int* __restrict__ w3,
                         const unsigned int* __restrict__ bb3,
                         const unsigned int* __restrict__ idx,
                         int* __restrict__ wsi){
  int t = threadIdx.x >> 6, lane = threadIdx.x & 63;
  if (t > 8) return;
  if (t == 8){
    unsigned long long nz = __ballot(idx[2 * lane + 1] != 0u);
    if (lane == 0) wsi[WS_FLG_I + 8] = (nz == 0ull) ? 1 : 0;
    return;
  }
  const unsigned int* ptrs[8] = {lat, act, w1, bb1, w2, bb2, w3, bb3};
  unsigned int u = ptrs[t][lane];
  unsigned int e = (u >> 7) & 0xFFu;
  unsigned long long ib = __ballot(e >= 100u && e <= 150u);
  if (lane == 0) wsi[WS_FLG_I + t] = (__popcll(ib) < 40) ? 1 : 0;  // 1 = fp32
}

// ---------- row sorting by outer policy: single block, LDS atomics ----------
// Replaces k_zero/k_count/k_scan/k_scatter. 8192 global same-line atomics
// (fully serialized at one L2 channel) -> 8192 LDS atomics (~cycles each).
__global__ void k_sort(const void* __restrict__ idx, int* __restrict__ wsi){
  __shared__ int hist[PNUM];
  __shared__ int cur[PNUM];
  const int tid = threadIdx.x;           // 1024 threads
  const int i64 = wsi[WS_FLG_I + 8];
  if (tid < PNUM) hist[tid] = 0;
  __syncthreads();
  int pol[8];
  #pragma unroll
  for (int c = 0; c < 8; c++){
    int t = c * 1024 + tid;
    pol[c] = ldidx(idx, t, i64);
    atomicAdd(&hist[pol[c]], 1);
  }
  __syncthreads();
  if (tid == 0){
    int off = 0;
    #pragma unroll
    for (int i = 0; i < PNUM; i++){
      int h = hist[i];
      wsi[WS_COUNTS_I + i] = h;
      wsi[WS_OFFS_I + i] = off;
      cur[i] = off;
      off += h;
    }
  }
  __syncthreads();
  #pragma unroll
  for (int c = 0; c < 8; c++){
    int t = c * 1024 + tid;
    int pos = atomicAdd(&cur[pol[c]], 1);
    wsi[WS_PERM_I + pos] = t;
  }
}

// ---------- weight packing, coalesced via LDS transpose ----------
__global__ void k_pack(const void* __restrict__ src, ushort* __restrict__ dst,
                       int Ksrc, int nks, int ntiles, int N,
                       const int* __restrict__ wsi, int flg){
  __shared__ ushort T[32][66];
  const int ks = blockIdx.y, pair = blockIdx.z, nt0 = blockIdx.x * 4;
  const int f32 = wsi[WS_FLG_I + flg];
  const int w = threadIdx.x >> 6, lane = threadIdx.x & 63;
  #pragma unroll
  for (int kk = 0; kk < 8; kk++){
    int krow = w * 8 + kk;
    int k = ks * 32 + krow;
    int n = nt0 * 16 + lane;
    ushort v = 0;
    if (k < Ksrc) v = f2bf(ldf(src, ((size_t)pair * Ksrc + k) * N + n, f32));
    T[krow][lane] = v;
  }
  __syncthreads();
  const int lm = lane & 15, lq = lane >> 4;
  unsigned int vv[4];
  #pragma unroll
  for (int j = 0; j < 4; j++){
    ushort lo = T[lq * 8 + 2 * j    ][w * 16 + lm];
    ushort hi = T[lq * 8 + 2 * j + 1][w * 16 + lm];
    vv[j] = pk2(lo, hi);
  }
  uint4 val = make_uint4(vv[0], vv[1], vv[2], vv[3]);
  size_t f = (size_t)(pair * nks + ks) * ntiles + (nt0 + w);
  *(uint4*)(dst + f * 512 + (size_t)lane * 8) = val;
}

// ---------- fused 3-layer MLP ----------
// v2: 512 threads (8 waves), same TM=32 / same LDS -> 2 blocks/CU = 16 waves/CU
// (was 8). Each wave owns 4 n-tiles outright (np loop removed). Layer-1
// weights fully preloaded before the X-stage barrier; layers 2/3 use depth-2
// weight prefetch; next layer's first weight frags hoisted above each barrier.
__global__ void __launch_bounds__(512, 4) k_mlp(
    const void* __restrict__ latents, const void* __restrict__ actions,
    const void* __restrict__ b1, const void* __restrict__ b2,
    const void* __restrict__ b3,
    const int* __restrict__ wsi,
    const ushort* __restrict__ w1p, const ushort* __restrict__ w2p,
    const ushort* __restrict__ w3p,
    void* __restrict__ out, int out_elems)
{
  __shared__ __align__(16) ushort Xb [TM * PXP];   // 6656 B
  __shared__ __align__(16) ushort H1s[TM * PHP];   // 33280 B
  __shared__ __align__(16) ushort H2s[TM * PHP];   // 33280 B
  __shared__ int rowid[TM];

  const int io = blockIdx.x >> 3, p = blockIdx.x & 7, tile = blockIdx.y;
  const int cnt = wsi[WS_COUNTS_I + io];
  if (tile * TM >= cnt) return;
  const int r0    = wsi[WS_OFFS_I + io] + tile * TM;
  const int mrows = min(TM, cnt - tile * TM);
  const int pair  = io * PNUM + p;
  const int tid   = threadIdx.x;
  const int fLat  = wsi[WS_FLG_I + 0];
  const int fAct  = wsi[WS_FLG_I + 1];
  const int fB1   = wsi[WS_FLG_I + 3];
  const int fB2   = wsi[WS_FLG_I + 5];
  const int fB3   = wsi[WS_FLG_I + 7];

  const int w = tid >> 6, lane = tid & 63;
  const int lm = lane & 15, lq = lane >> 4;
  const int ntb = w * 4;
  const uint4* w1v = (const uint4*)w1p;
  const uint4* w2v = (const uint4*)w2p;
  const uint4* w3v = (const uint4*)w3p;
  const f32x4 zero4 = {0.f, 0.f, 0.f, 0.f};

  // ---- preload ALL layer-1 weights for this wave's 4 n-tiles (12 uint4),
  // issued before the X staging so they fly during staging + barrier.
  uint4 a1w[NKS1][4];
  #pragma unroll
  for (int ks = 0; ks < NKS1; ks++)
    #pragma unroll
    for (int a = 0; a < 4; a++)
      a1w[ks][a] = w1v[((size_t)(pair * NKS1 + ks) * NT12 + ntb + a) * 64 + lane];

  // ---- stage X tile: TM rows, chunks of 8 elems (64 lat + 8 act + 24 zero)
  for (int task = tid; task < TM * 16; task += 512){
    int r = task >> 4, c = task & 15;
    if (c >= 13) continue;
    uint4 val = make_uint4(0u, 0u, 0u, 0u);
    if (r < mrows){
      int row = wsi[WS_PERM_I + r0 + r];
      if (c == 8) rowid[r] = row;
      if (c < 9){
        int f32 = (c < 8) ? fLat : fAct;
        if (f32){
          const float* sf = (c < 8)
            ? ((const float*)latents + (size_t)row * DDIM + p * ZDIM + c * 8)
            : ((const float*)actions + (size_t)row * ADIM);
          float4 f0 = *(const float4*)sf;
          float4 f1 = *(const float4*)(sf + 4);
          val = make_uint4(pk2(f2bf(f0.x), f2bf(f0.y)),
                           pk2(f2bf(f0.z), f2bf(f0.w)),
                           pk2(f2bf(f1.x), f2bf(f1.y)),
                           pk2(f2bf(f1.z), f2bf(f1.w)));
        } else {
          const ushort* sh = (c < 8)
            ? ((const ushort*)latents + (size_t)row * DDIM + p * ZDIM + c * 8)
            : ((const ushort*)actions + (size_t)row * ADIM);
          val = *(const uint4*)sh;
        }
      }
    } else if (c == 8) rowid[r] = 0;
    *(uint4*)(Xb + r * PXP + c * 8) = val;
  }
  __syncthreads();

  #define MFMA8(A, B) \
    { _Pragma("unroll") for (int a_ = 0; a_ < 4; a_++) \
      { _Pragma("unroll") for (int m_ = 0; m_ < 2; m_++) \
        acc[a_][m_] = __builtin_amdgcn_mfma_f32_16x16x32_bf16( \
            __builtin_bit_cast(bf16x8, A[a_]), __builtin_bit_cast(bf16x8, B[m_]), \
            acc[a_][m_], 0, 0, 0); } }
  #define LDA2(dst, kss) \
    { _Pragma("unroll") for (int a_ = 0; a_ < 4; a_++) \
        dst[a_] = w2v[((size_t)(pair * NKS2 + (kss)) * NT12 + ntb + a_) * 64 + lane]; }
  #define LDB2(dst, kss) \
    { _Pragma("unroll") for (int m_ = 0; m_ < 2; m_++) \
        dst[m_] = *(const uint4*)(H1s + (size_t)(m_ * 16 + lm) * PHP + (kss) * 32 + lq * 8); }
  #define CP4(dst, srcv) \
    { _Pragma("unroll") for (int a_ = 0; a_ < 4; a_++) dst[a_] = srcv[a_]; }

  // ================= layer 1: Xb(TMx96) -> H1(TMx512), relu =================
  {
    f32x4 acc[4][2];
    #pragma unroll
    for (int a = 0; a < 4; a++)
      #pragma unroll
      for (int m = 0; m < 2; m++) acc[a][m] = zero4;

    #pragma unroll
    for (int ks = 0; ks < NKS1; ks++){
      uint4 bfm[2];
      #pragma unroll
      for (int m = 0; m < 2; m++)
        bfm[m] = *(const uint4*)(Xb + (size_t)(m * 16 + lm) * PXP + ks * 32 + lq * 8);
      MFMA8(a1w[ks], bfm);
    }
    #pragma unroll
    for (int a = 0; a < 4; a++){
      int n0 = (ntb + a) * 16 + lq * 4;
      float4 bq = ldbias4(b1, (size_t)pair * HDIM + n0, fB1);
      #pragma unroll
      for (int m = 0; m < 2; m++){
        ushort4 o;
        o.x = f2bf(fmaxf(acc[a][m][0] + bq.x, 0.f));
        o.y = f2bf(fmaxf(acc[a][m][1] + bq.y, 0.f));
        o.z = f2bf(fmaxf(acc[a][m][2] + bq.z, 0.f));
        o.w = f2bf(fmaxf(acc[a][m][3] + bq.w, 0.f));
        *(ushort4*)(H1s + (size_t)(m * 16 + lm) * PHP + n0) = o;
      }
    }
  }

  // hoist layer-2 first weight frags above the barrier (global, no LDS dep)
  uint4 A0[4], A1[4];
  LDA2(A0, 0);
  LDA2(A1, 1);
  __syncthreads();

  // ================= layer 2: H1 -> H2, relu (depth-2 weight prefetch) =======
  {
    f32x4 acc[4][2];
    #pragma unroll
    for (int a = 0; a < 4; a++)
      #pragma unroll
      for (int m = 0; m < 2; m++) acc[a][m] = zero4;

    uint4 B0[2], B1[2];
    LDB2(B0, 0);
    #pragma unroll
    for (int ks = 0; ks < NKS2; ks += 2){
      uint4 TA[4];
      if (ks + 2 < NKS2) LDA2(TA, ks + 2);
      LDB2(B1, ks + 1);
      MFMA8(A0, B0);
      if (ks + 2 < NKS2) CP4(A0, TA);
      uint4 TB[4];
      if (ks + 3 < NKS2) LDA2(TB, ks + 3);
      if (ks + 2 < NKS2) LDB2(B0, ks + 2);
      MFMA8(A1, B1);
      if (ks + 3 < NKS2) CP4(A1, TB);
    }
    #pragma unroll
    for (int a = 0; a < 4; a++){
      int n0 = (ntb + a) * 16 + lq * 4;
      float4 bq = ldbias4(b2, (size_t)pair * HDIM + n0, fB2);
      #pragma unroll
      for (int m = 0; m < 2; m++){
        ushort4 o;
        o.x = f2bf(fmaxf(acc[a][m][0] + bq.x, 0.f));
        o.y = f2bf(fmaxf(acc[a][m][1] + bq.y, 0.f));
        o.z = f2bf(fmaxf(acc[a][m][2] + bq.z, 0.f));
        o.w = f2bf(fmaxf(acc[a][m][3] + bq.w, 0.f));
        *(ushort4*)(H2s + (size_t)(m * 16 + lm) * PHP + n0) = o;
      }
    }
  }

  // layer 3 split over 8 waves: wave w owns (z-tile w&3, m-half w>>2)
  const int zt = w & 3, mh = w >> 2;
  uint4 C0 = w3v[((size_t)(pair * NKS3 + 0) * NT3 + zt) * 64 + lane];
  uint4 C1 = w3v[((size_t)(pair * NKS3 + 1) * NT3 + zt) * 64 + lane];
  __syncthreads();

  // ================= layer 3: H2 -> out (depth-2 weight prefetch) ===========
  {
    f32x4 acc3 = zero4;
    #pragma unroll
    for (int ks = 0; ks < NKS3; ks += 2){
      uint4 T0;
      if (ks + 2 < NKS3)
        T0 = w3v[((size_t)(pair * NKS3 + ks + 2) * NT3 + zt) * 64 + lane];
      uint4 bf = *(const uint4*)(H2s + (size_t)(mh * 16 + lm) * PHP + ks * 32 + lq * 8);
      acc3 = __builtin_amdgcn_mfma_f32_16x16x32_bf16(
          __builtin_bit_cast(bf16x8, C0), __builtin_bit_cast(bf16x8, bf), acc3, 0, 0, 0);
      if (ks + 2 < NKS3) C0 = T0;
      uint4 T1;
      if (ks + 3 < NKS3)
        T1 = w3v[((size_t)(pair * NKS3 + ks + 3) * NT3 + zt) * 64 + lane];
      uint4 bf2 = *(const uint4*)(H2s + (size_t)(mh * 16 + lm) * PHP + (ks + 1) * 32 + lq * 8);
      acc3 = __builtin_amdgcn_mfma_f32_16x16x32_bf16(
          __builtin_bit_cast(bf16x8, C1), __builtin_bit_cast(bf16x8, bf2), acc3, 0, 0, 0);
      if (ks + 3 < NKS3) C1 = T1;
    }
    int z0 = zt * 16 + lq * 4;
    float4 bq = ldbias4(b3, (size_t)pair * ZDIM + z0, fB3);
    int mm = mh * 16 + lm;
    if (mm < mrows){
      int row = rowid[mm];
      size_t oidx = (size_t)row * DDIM + p * ZDIM + z0;
      if (oidx + 4 <= (size_t)out_elems){
        if (fLat){   // latents fp32 -> output fp32 (ref: zeros_like(latents))
          float4 o;
          o.x = acc3[0] + bq.x;
          o.y = acc3[1] + bq.y;
          o.z = acc3[2] + bq.z;
          o.w = acc3[3] + bq.w;
          *(float4*)((float*)out + oidx) = o;
        } else {
          ushort4 o;
          o.x = f2bf(acc3[0] + bq.x);
          o.y = f2bf(acc3[1] + bq.y);
          o.z = f2bf(acc3[2] + bq.z);
          o.w = f2bf(acc3[3] + bq.w);
          *(ushort4*)((ushort*)out + oidx) = o;
        }
      }
    }
  }
  #undef MFMA8
  #undef LDA2
  #undef LDB2
  #undef CP4
}

extern "C" void kernel_launch(void* const* d_in, const int* in_sizes, int n_in,
                              void* d_out, int out_size, void* d_ws, size_t ws_size,
                              hipStream_t stream){
  if (n_in < 9) return;
  const void* latents = d_in[0];
  const void* actions = d_in[1];
  const void* pidx    = d_in[2];
  const void* W1      = d_in[3];
  const void* b1      = d_in[4];
  const void* W2      = d_in[5];
  const void* b2      = d_in[6];
  const void* W3      = d_in[7];
  const void* b3      = d_in[8];

  if (ws_size < (size_t)WS_NEED_B) return;

  int*    wsi = (int*)d_ws;
  char*   wsb = (char*)d_ws;
  ushort* w1p = (ushort*)(wsb + WS_W1P_B);
  ushort* w2p = (ushort*)(wsb + WS_W2P_B);
  ushort* w3p = (ushort*)(wsb + WS_W3P_B);

  k_detect <<<1, 576, 0, stream>>>(
      (const unsigned int*)latents, (const unsigned int*)actions,
      (const unsigned int*)W1, (const unsigned int*)b1,
      (const unsigned int*)W2, (const unsigned int*)b2,
      (const unsigned int*)W3, (const unsigned int*)b3,
      (const unsigned int*)pidx, wsi);
  k_sort   <<<1, 1024, 0, stream>>>(pidx, wsi);
  k_pack<<<dim3(8, NKS1, 64), 256, 0, stream>>>(W1, w1p, KIN,  NKS1, NT12, HDIM, wsi, 2);
  k_pack<<<dim3(8, NKS2, 64), 256, 0, stream>>>(W2, w2p, HDIM, NKS2, NT12, HDIM, wsi, 4);
  k_pack<<<dim3(1, NKS3, 64), 256, 0, stream>>>(W3, w3p, HDIM, NKS3, NT3,  ZDIM, wsi, 6);
  k_mlp<<<dim3(64, BATCH/TM), 512, 0, stream>>>(
      latents, actions, b1, b2, b3, wsi, w1p, w2p, w3p, d_out, out_size);
}

// Round 2
// 219.297 us; speedup vs baseline: 1.7490x; 1.1821x over previous
//
#include <hip/hip_runtime.h>
#include <stdint.h>

// ---- problem constants ----
#define PNUM  8
#define DDIM  512
#define ZDIM  64
#define ADIM  8
#define HDIM  512
#define BATCH 8192
#define KIN   72     // Z + A
#define NKS1  3      // layer1 k-steps of 32 (K padded 72->96)
#define NKS2  16     // layer2 k-steps (K=512)
#define NKS3  16     // layer3 k-steps (K=512)
#define NT12  32     // 512/16 neuron tiles (layers 1,2)
#define NT3   4      // 64/16 z tiles (layer 3)
#define TM    64     // batch rows per block (64: 146.7KB LDS, 1 block/CU, 2x MFMA per weight byte)
#define PXP   104    // Xb pitch (bf16 elems): 96 data + 8 pad
#define PHP   520    // H pitch: 512 + 8 pad

typedef __attribute__((ext_vector_type(8))) __bf16 bf16x8;
typedef __attribute__((ext_vector_type(4))) float  f32x4;

// ---- workspace layout ----
#define WS_COUNTS_I 0      // 8 counts
#define WS_OFFS_I   16     // 8 offsets
#define WS_CURS_I   32     // (unused, kept for layout stability)
#define WS_FLG_I    42     // 9 flags: 0=lat,1=act,2=W1,3=b1,4=W2,5=b2,6=W3,7=b3 (1=fp32,0=bf16); 8=idx64
#define WS_PERM_I   64     // 8192 row ids
#define WS_W1P_B    40960
#define WS_W2P_B    (WS_W1P_B + 64*NKS1*NT12*1024)            // +6291456
#define WS_W3P_B    (WS_W2P_B + 64*NKS2*NT12*1024)            // +33554432
#define WS_NEED_B   (WS_W3P_B + 64*NKS3*NT3*1024)             // -> 44081152

__device__ __forceinline__ float bf2f(ushort h){
  union { unsigned int u; float f; } v; v.u = ((unsigned int)h) << 16; return v.f;
}
__device__ __forceinline__ ushort f2bf(float f){
  union { float f; unsigned int u; } v; v.f = f;
  unsigned int u = v.u;
  return (ushort)((u + 0x7FFFu + ((u >> 16) & 1u)) >> 16);  // RNE
}
__device__ __forceinline__ unsigned int pk2(ushort lo, ushort hi){
  return (unsigned int)lo | ((unsigned int)hi << 16);
}
__device__ __forceinline__ int ldidx(const void* p, int t, int i64){
  return i64 ? (int)((const long long*)p)[t] : ((const int*)p)[t];
}
__device__ __forceinline__ float4 ldbias4(const void* b, size_t off, int f32){
  if (f32) return *(const float4*)((const float*)b + off);
  ushort4 q = *(const ushort4*)((const ushort*)b + off);
  float4 r; r.x = bf2f(q.x); r.y = bf2f(q.y); r.z = bf2f(q.z); r.w = bf2f(q.w);
  return r;
}

// ---------- prep: dtype detection + row sort, one block ----------
__global__ void k_prep(const unsigned int* __restrict__ lat,
                       const unsigned int* __restrict__ act,
                       const unsigned int* __restrict__ w1,
                       const unsigned int* __restrict__ bb1,
                       const unsigned int* __restrict__ w2,
                       const unsigned int* __restrict__ bb2,
                       const unsigned int* __restrict__ w3,
                       const unsigned int* __restrict__ bb3,
                       const void* __restrict__ idx,
                       int* __restrict__ wsi){
  __shared__ int hist[PNUM];
  __shared__ int cur[PNUM];
  __shared__ int flg_i64;
  const int tid = threadIdx.x;           // 1024 threads, 16 waves
  if (tid < PNUM) hist[tid] = 0;
  const int t = tid >> 6, lane = tid & 63;
  if (t == 8){
    unsigned long long nz = __ballot(((const unsigned int*)idx)[2 * lane + 1] != 0u);
    if (lane == 0){ int v = (nz == 0ull) ? 1 : 0; wsi[WS_FLG_I + 8] = v; flg_i64 = v; }
  } else if (t < 8){
    const unsigned int* ptrs[8] = {lat, act, w1, bb1, w2, bb2, w3, bb3};
    unsigned int u = ptrs[t][lane];
    unsigned int e = (u >> 7) & 0xFFu;
    unsigned long long ib = __ballot(e >= 100u && e <= 150u);
    if (lane == 0) wsi[WS_FLG_I + t] = (__popcll(ib) < 40) ? 1 : 0;  // 1 = fp32
  }
  __syncthreads();
  const int i64 = flg_i64;
  int pol[8];
  #pragma unroll
  for (int c = 0; c < 8; c++){
    pol[c] = ldidx(idx, c * 1024 + tid, i64);
    atomicAdd(&hist[pol[c]], 1);
  }
  __syncthreads();
  if (tid == 0){
    int off = 0;
    #pragma unroll
    for (int i = 0; i < PNUM; i++){
      int h = hist[i];
      wsi[WS_COUNTS_I + i] = h;
      wsi[WS_OFFS_I + i] = off;
      cur[i] = off;
      off += h;
    }
  }
  __syncthreads();
  #pragma unroll
  for (int c = 0; c < 8; c++){
    int pos = atomicAdd(&cur[pol[c]], 1);
    wsi[WS_PERM_I + pos] = c * 1024 + tid;
  }
}

// ---------- all three weight packs in one launch, vectorized reads ----------
// Block: 64 n x 32 k of one (pair, ks). W1: 1536 blocks, W2: 8192, W3: 1024.
#define PK_W1_N  1536
#define PK_W2_N  8192
#define PK_W3_N  1024
__global__ void k_pack_all(const void* __restrict__ W1, const void* __restrict__ W2,
                           const void* __restrict__ W3,
                           ushort* __restrict__ w1p, ushort* __restrict__ w2p,
                           ushort* __restrict__ w3p,
                           const int* __restrict__ wsi){
  __shared__ ushort T[32][80];   // pitch 80 ushorts (160B, 16B-aligned rows)
  int bid = blockIdx.x;
  const void* src; ushort* dst;
  int Ksrc, nks, ntiles, N, flg, ntg, ks, pair;
  if (bid < PK_W1_N){
    src = W1; dst = w1p; Ksrc = KIN;  nks = NKS1; ntiles = NT12; N = HDIM; flg = 2;
    pair = bid / 24; int rem = bid % 24; ks = rem >> 3; ntg = rem & 7;
  } else if (bid < PK_W1_N + PK_W2_N){
    int local = bid - PK_W1_N;
    src = W2; dst = w2p; Ksrc = HDIM; nks = NKS2; ntiles = NT12; N = HDIM; flg = 4;
    pair = local / 128; int rem = local % 128; ks = rem >> 3; ntg = rem & 7;
  } else {
    int local = bid - PK_W1_N - PK_W2_N;
    src = W3; dst = w3p; Ksrc = HDIM; nks = NKS3; ntiles = NT3;  N = ZDIM; flg = 6;
    pair = local / 16; ks = local % 16; ntg = 0;
  }
  const int f32 = wsi[WS_FLG_I + flg];
  const int tid = threadIdx.x;
  const int nb = ntg * 64;        // n-base of this block

  if (f32){
    #pragma unroll
    for (int it = 0; it < 2; it++){
      int i = it * 256 + tid;          // 512 float4 = 64n x 32k
      int k = i >> 4, nq = i & 15;
      int kk = ks * 32 + k;
      float4 v = make_float4(0.f, 0.f, 0.f, 0.f);
      if (kk < Ksrc)
        v = *(const float4*)((const float*)src + ((size_t)pair * Ksrc + kk) * N + nb + nq * 4);
      ushort4 o; o.x = f2bf(v.x); o.y = f2bf(v.y); o.z = f2bf(v.z); o.w = f2bf(v.w);
      *(ushort4*)&T[k][nq * 4] = o;
    }
  } else {
    int k = tid >> 3, uq = tid & 7;    // 256 uint4 = 64n x 32k
    int kk = ks * 32 + k;
    uint4 v = make_uint4(0u, 0u, 0u, 0u);
    if (kk < Ksrc)
      v = *(const uint4*)((const ushort*)src + ((size_t)pair * Ksrc + kk) * N + nb + uq * 8);
    *(uint4*)&T[k][uq * 8] = v;
  }
  __syncthreads();

  const int w = tid >> 6, lane = tid & 63;
  const int lm = lane & 15, lq = lane >> 4;
  unsigned int vv[4];
  #pragma unroll
  for (int j = 0; j < 4; j++){
    ushort lo = T[lq * 8 + 2 * j    ][w * 16 + lm];
    ushort hi = T[lq * 8 + 2 * j + 1][w * 16 + lm];
    vv[j] = pk2(lo, hi);
  }
  uint4 val = make_uint4(vv[0], vv[1], vv[2], vv[3]);
  size_t f = (size_t)(pair * nks + ks) * ntiles + (ntg * 4 + w);
  *(uint4*)(dst + f * 512 + (size_t)lane * 8) = val;
}

// ---------- fused 3-layer MLP ----------
// v3: TM=64 (m=4 quarters). 1 block/CU (146.7KB LDS), 8 waves. Halves L2
// weight traffic per FLOP vs TM=32: per k-step a wave does 16 MFMA on
// 4 weight frags (was 8 on 4). Grid 64x128 -> ~1024+ active blocks = 4/CU.
__global__ void __launch_bounds__(512, 2) k_mlp(
    const void* __restrict__ latents, const void* __restrict__ actions,
    const void* __restrict__ b1, const void* __restrict__ b2,
    const void* __restrict__ b3,
    const int* __restrict__ wsi,
    const ushort* __restrict__ w1p, const ushort* __restrict__ w2p,
    const ushort* __restrict__ w3p,
    void* __restrict__ out, int out_elems)
{
  __shared__ __align__(16) ushort Xb [TM * PXP];   // 13312 B
  __shared__ __align__(16) ushort H1s[TM * PHP];   // 66560 B
  __shared__ __align__(16) ushort H2s[TM * PHP];   // 66560 B
  __shared__ int rowid[TM];

  const int io = blockIdx.x >> 3, p = blockIdx.x & 7, tile = blockIdx.y;
  const int cnt = wsi[WS_COUNTS_I + io];
  if (tile * TM >= cnt) return;
  const int r0    = wsi[WS_OFFS_I + io] + tile * TM;
  const int mrows = min(TM, cnt - tile * TM);
  const int pair  = io * PNUM + p;
  const int tid   = threadIdx.x;
  const int fLat  = wsi[WS_FLG_I + 0];
  const int fAct  = wsi[WS_FLG_I + 1];
  const int fB1   = wsi[WS_FLG_I + 3];
  const int fB2   = wsi[WS_FLG_I + 5];
  const int fB3   = wsi[WS_FLG_I + 7];

  const int w = tid >> 6, lane = tid & 63;
  const int lm = lane & 15, lq = lane >> 4;
  const int ntb = w * 4;
  const uint4* w1v = (const uint4*)w1p;
  const uint4* w2v = (const uint4*)w2p;
  const uint4* w3v = (const uint4*)w3p;
  const f32x4 zero4 = {0.f, 0.f, 0.f, 0.f};

  // ---- preload ALL layer-1 weights (12 uint4) + layer-1 biases: fly during staging
  uint4 a1w[NKS1][4];
  #pragma unroll
  for (int ks = 0; ks < NKS1; ks++)
    #pragma unroll
    for (int a = 0; a < 4; a++)
      a1w[ks][a] = w1v[((size_t)(pair * NKS1 + ks) * NT12 + ntb + a) * 64 + lane];
  float4 bq1[4];
  #pragma unroll
  for (int a = 0; a < 4; a++)
    bq1[a] = ldbias4(b1, (size_t)pair * HDIM + (ntb + a) * 16 + lq * 4, fB1);

  // ---- stage X tile: TM rows, chunks of 8 elems (64 lat + 8 act + 24 zero)
  for (int task = tid; task < TM * 16; task += 512){
    int r = task >> 4, c = task & 15;
    if (c >= 13) continue;
    uint4 val = make_uint4(0u, 0u, 0u, 0u);
    if (r < mrows){
      int row = wsi[WS_PERM_I + r0 + r];
      if (c == 8) rowid[r] = row;
      if (c < 9){
        int f32 = (c < 8) ? fLat : fAct;
        if (f32){
          const float* sf = (c < 8)
            ? ((const float*)latents + (size_t)row * DDIM + p * ZDIM + c * 8)
            : ((const float*)actions + (size_t)row * ADIM);
          float4 f0 = *(const float4*)sf;
          float4 f1 = *(const float4*)(sf + 4);
          val = make_uint4(pk2(f2bf(f0.x), f2bf(f0.y)),
                           pk2(f2bf(f0.z), f2bf(f0.w)),
                           pk2(f2bf(f1.x), f2bf(f1.y)),
                           pk2(f2bf(f1.z), f2bf(f1.w)));
        } else {
          const ushort* sh = (c < 8)
            ? ((const ushort*)latents + (size_t)row * DDIM + p * ZDIM + c * 8)
            : ((const ushort*)actions + (size_t)row * ADIM);
          val = *(const uint4*)sh;
        }
      }
    } else if (c == 8) rowid[r] = 0;
    *(uint4*)(Xb + r * PXP + c * 8) = val;
  }
  __syncthreads();

  #define MFMA16(A, B) \
    { _Pragma("unroll") for (int a_ = 0; a_ < 4; a_++) \
      { _Pragma("unroll") for (int m_ = 0; m_ < 4; m_++) \
        acc[a_][m_] = __builtin_amdgcn_mfma_f32_16x16x32_bf16( \
            __builtin_bit_cast(bf16x8, A[a_]), __builtin_bit_cast(bf16x8, B[m_]), \
            acc[a_][m_], 0, 0, 0); } }
  #define LDA2(dst, kss) \
    { _Pragma("unroll") for (int a_ = 0; a_ < 4; a_++) \
        dst[a_] = w2v[((size_t)(pair * NKS2 + (kss)) * NT12 + ntb + a_) * 64 + lane]; }
  #define LDB4(dst, kss) \
    { _Pragma("unroll") for (int m_ = 0; m_ < 4; m_++) \
        dst[m_] = *(const uint4*)(H1s + (size_t)(m_ * 16 + lm) * PHP + (kss) * 32 + lq * 8); }
  #define CP4(dst, srcv) \
    { _Pragma("unroll") for (int a_ = 0; a_ < 4; a_++) dst[a_] = srcv[a_]; }

  // ================= layer 1: Xb(TMx96) -> H1(TMx512), relu =================
  {
    f32x4 acc[4][4];
    #pragma unroll
    for (int a = 0; a < 4; a++)
      #pragma unroll
      for (int m = 0; m < 4; m++) acc[a][m] = zero4;

    #pragma unroll
    for (int ks = 0; ks < NKS1; ks++){
      uint4 bfm[4];
      #pragma unroll
      for (int m = 0; m < 4; m++)
        bfm[m] = *(const uint4*)(Xb + (size_t)(m * 16 + lm) * PXP + ks * 32 + lq * 8);
      MFMA16(a1w[ks], bfm);
    }
    #pragma unroll
    for (int a = 0; a < 4; a++){
      int n0 = (ntb + a) * 16 + lq * 4;
      #pragma unroll
      for (int m = 0; m < 4; m++){
        ushort4 o;
        o.x = f2bf(fmaxf(acc[a][m][0] + bq1[a].x, 0.f));
        o.y = f2bf(fmaxf(acc[a][m][1] + bq1[a].y, 0.f));
        o.z = f2bf(fmaxf(acc[a][m][2] + bq1[a].z, 0.f));
        o.w = f2bf(fmaxf(acc[a][m][3] + bq1[a].w, 0.f));
        *(ushort4*)(H1s + (size_t)(m * 16 + lm) * PHP + n0) = o;
      }
    }
  }

  // hoist layer-2 first weight frags + biases above the barrier
  uint4 A0[4], A1[4];
  LDA2(A0, 0);
  LDA2(A1, 1);
  float4 bq2[4];
  #pragma unroll
  for (int a = 0; a < 4; a++)
    bq2[a] = ldbias4(b2, (size_t)pair * HDIM + (ntb + a) * 16 + lq * 4, fB2);
  __syncthreads();

  // ================= layer 2: H1 -> H2, relu (depth-2 weight prefetch) =======
  {
    f32x4 acc[4][4];
    #pragma unroll
    for (int a = 0; a < 4; a++)
      #pragma unroll
      for (int m = 0; m < 4; m++) acc[a][m] = zero4;

    uint4 B0[4], B1[4];
    LDB4(B0, 0);
    #pragma unroll
    for (int ks = 0; ks < NKS2; ks += 2){
      uint4 TA[4];
      if (ks + 2 < NKS2) LDA2(TA, ks + 2);
      LDB4(B1, ks + 1);
      MFMA16(A0, B0);
      if (ks + 2 < NKS2) CP4(A0, TA);
      uint4 TB[4];
      if (ks + 3 < NKS2) LDA2(TB, ks + 3);
      if (ks + 2 < NKS2) LDB4(B0, ks + 2);
      MFMA16(A1, B1);
      if (ks + 3 < NKS2) CP4(A1, TB);
    }
    #pragma unroll
    for (int a = 0; a < 4; a++){
      int n0 = (ntb + a) * 16 + lq * 4;
      #pragma unroll
      for (int m = 0; m < 4; m++){
        ushort4 o;
        o.x = f2bf(fmaxf(acc[a][m][0] + bq2[a].x, 0.f));
        o.y = f2bf(fmaxf(acc[a][m][1] + bq2[a].y, 0.f));
        o.z = f2bf(fmaxf(acc[a][m][2] + bq2[a].z, 0.f));
        o.w = f2bf(fmaxf(acc[a][m][3] + bq2[a].w, 0.f));
        *(ushort4*)(H2s + (size_t)(m * 16 + lm) * PHP + n0) = o;
      }
    }
  }

  // layer 3 split over 8 waves: wave w owns z-tile (w&3), m-quarters (w>>2, w>>2+2)
  const int zt = w & 3, mb = w >> 2;
  uint4 C0 = w3v[((size_t)(pair * NKS3 + 0) * NT3 + zt) * 64 + lane];
  uint4 C1 = w3v[((size_t)(pair * NKS3 + 1) * NT3 + zt) * 64 + lane];
  float4 bq3 = ldbias4(b3, (size_t)pair * ZDIM + zt * 16 + lq * 4, fB3);
  __syncthreads();

  // ================= layer 3: H2 -> out (depth-2 weight prefetch) ===========
  {
    f32x4 acc3[2];
    acc3[0] = zero4; acc3[1] = zero4;
    #pragma unroll
    for (int ks = 0; ks < NKS3; ks += 2){
      uint4 T0, T1;
      if (ks + 2 < NKS3)
        T0 = w3v[((size_t)(pair * NKS3 + ks + 2) * NT3 + zt) * 64 + lane];
      if (ks + 3 < NKS3)
        T1 = w3v[((size_t)(pair * NKS3 + ks + 3) * NT3 + zt) * 64 + lane];
      #pragma unroll
      for (int h = 0; h < 2; h++){
        int row = (mb + 2 * h) * 16 + lm;
        uint4 bf = *(const uint4*)(H2s + (size_t)row * PHP + ks * 32 + lq * 8);
        acc3[h] = __builtin_amdgcn_mfma_f32_16x16x32_bf16(
            __builtin_bit_cast(bf16x8, C0), __builtin_bit_cast(bf16x8, bf), acc3[h], 0, 0, 0);
      }
      #pragma unroll
      for (int h = 0; h < 2; h++){
        int row = (mb + 2 * h) * 16 + lm;
        uint4 bf = *(const uint4*)(H2s + (size_t)row * PHP + (ks + 1) * 32 + lq * 8);
        acc3[h] = __builtin_amdgcn_mfma_f32_16x16x32_bf16(
            __builtin_bit_cast(bf16x8, C1), __builtin_bit_cast(bf16x8, bf), acc3[h], 0, 0, 0);
      }
      if (ks + 2 < NKS3) C0 = T0;
      if (ks + 3 < NKS3) C1 = T1;
    }
    int z0 = zt * 16 + lq * 4;
    #pragma unroll
    for (int h = 0; h < 2; h++){
      int mm = (mb + 2 * h) * 16 + lm;
      if (mm < mrows){
        int row = rowid[mm];
        size_t oidx = (size_t)row * DDIM + p * ZDIM + z0;
        if (oidx + 4 <= (size_t)out_elems){
          if (fLat){   // latents fp32 -> output fp32 (ref: zeros_like(latents))
            float4 o;
            o.x = acc3[h][0] + bq3.x;
            o.y = acc3[h][1] + bq3.y;
            o.z = acc3[h][2] + bq3.z;
            o.w = acc3[h][3] + bq3.w;
            *(float4*)((float*)out + oidx) = o;
          } else {
            ushort4 o;
            o.x = f2bf(acc3[h][0] + bq3.x);
            o.y = f2bf(acc3[h][1] + bq3.y);
            o.z = f2bf(acc3[h][2] + bq3.z);
            o.w = f2bf(acc3[h][3] + bq3.w);
            *(ushort4*)((ushort*)out + oidx) = o;
          }
        }
      }
    }
  }
  #undef MFMA16
  #undef LDA2
  #undef LDB4
  #undef CP4
}

extern "C" void kernel_launch(void* const* d_in, const int* in_sizes, int n_in,
                              void* d_out, int out_size, void* d_ws, size_t ws_size,
                              hipStream_t stream){
  if (n_in < 9) return;
  const void* latents = d_in[0];
  const void* actions = d_in[1];
  const void* pidx    = d_in[2];
  const void* W1      = d_in[3];
  const void* b1      = d_in[4];
  const void* W2      = d_in[5];
  const void* b2      = d_in[6];
  const void* W3      = d_in[7];
  const void* b3      = d_in[8];

  if (ws_size < (size_t)WS_NEED_B) return;

  int*    wsi = (int*)d_ws;
  char*   wsb = (char*)d_ws;
  ushort* w1p = (ushort*)(wsb + WS_W1P_B);
  ushort* w2p = (ushort*)(wsb + WS_W2P_B);
  ushort* w3p = (ushort*)(wsb + WS_W3P_B);

  k_prep<<<1, 1024, 0, stream>>>(
      (const unsigned int*)latents, (const unsigned int*)actions,
      (const unsigned int*)W1, (const unsigned int*)b1,
      (const unsigned int*)W2, (const unsigned int*)b2,
      (const unsigned int*)W3, (const unsigned int*)b3,
      pidx, wsi);
  k_pack_all<<<PK_W1_N + PK_W2_N + PK_W3_N, 256, 0, stream>>>(
      W1, W2, W3, w1p, w2p, w3p, wsi);
  k_mlp<<<dim3(64, BATCH/TM), 512, 0, stream>>>(
      latents, actions, b1, b2, b3, wsi, w1p, w2p, w3p, d_out, out_size);
}